// Round 12
// baseline (684.987 us; speedup 1.0000x reference)
//
#include <hip/hip_runtime.h>
#include <cstdint>
#include <cstddef>

typedef __attribute__((ext_vector_type(8))) short bf16x8;
typedef __attribute__((ext_vector_type(4))) float f32x4;
typedef __attribute__((ext_vector_type(2))) float f32x2;

__device__ inline short bf16_rne(float f) {
  unsigned u = __builtin_bit_cast(unsigned, f);
  u += 0x7fff + ((u >> 16) & 1);
  return (short)(u >> 16);
}

__device__ inline float bf16lo(unsigned v) { return __builtin_bit_cast(float, v << 16); }
__device__ inline float bf16hi(unsigned v) { return __builtin_bit_cast(float, v & 0xffff0000u); }

__device__ inline unsigned pack2(float a, float b) {
  return ((unsigned)(unsigned short)bf16_rne(a)) | (((unsigned)(unsigned short)bf16_rne(b)) << 16);
}

// device-scope grid barrier: monotonic counter, release/acquire fences.
// SAFE only because grid == 6 blocks/CU * 256 CUs co-resident (launch_bounds(256,6)).
__device__ inline void gsync(int* bar, int target) {
  __syncthreads();
  if (threadIdx.x == 0) {
    __threadfence();                       // release: make prior writes device-visible
    atomicAdd(bar, 1);
    while (atomicAdd(bar, 0) < target) __builtin_amdgcn_s_sleep(2);
    __threadfence();                       // acquire: invalidate stale cached lines
  }
  __syncthreads();
}

// ================= fused graph pipeline =================
// Phase A: pack W1/W2 + bias2 + convert x (bf16 + fp8) + zero bucket counters
// Phase B: bucket scatter into slack regions (128-node buckets)
// Phase C: per-bucket CSR finalize
// Phase D: layer-1 mean aggregation (quad-mode fp8 gather) -> bf16 A1 right half
__global__ __launch_bounds__(256, 6) void pipeline_kernel(
    const float* __restrict__ W1, const float* __restrict__ W2,
    const float* __restrict__ b2, const float* __restrict__ x,
    short* __restrict__ B1p, short* __restrict__ B2p, float* __restrict__ bias2,
    unsigned* __restrict__ A1u, unsigned* __restrict__ xf8, int nquads,
    const int* __restrict__ esrc, const int* __restrict__ edst, int E, int EPB,
    int* __restrict__ counters, int NB, int SLACK, unsigned* __restrict__ bedge, int SB,
    int* __restrict__ offsets, int* __restrict__ oend, float* __restrict__ inv_deg,
    int* __restrict__ ssrc, int N, int* __restrict__ bar) {
  __shared__ int sm[1024];
  int tid = threadIdx.x;
  int G = gridDim.x;

  // ---------- Phase A: prep ----------
  int nqb = (nquads + 255) >> 8;
  int totalA = 513 + nqb + 1;
  for (int b = blockIdx.x; b < totalA; b += G) {
    if (b < 512) {
      int mode = b >> 8;
      int idx = (b & 255) * 256 + tid;
      int j = idx & 7;
      int L = (idx >> 3) & 63;
      int nt = (idx >> 9) & 15;
      int kb = idx >> 13;
      int k = kb * 32 + (L >> 4) * 8 + j;
      int n = nt * 16 + (L & 15);
      if (mode == 0) {
        B1p[idx] = bf16_rne(W1[(size_t)k * 256 + n]);
      } else {
        float v = (n < 128) ? W2[(size_t)k * 128 + n] : W2[(size_t)(256 + k) * 128 + (n - 128)];
        B2p[idx] = bf16_rne(v);
      }
    } else if (b == 512) {
      bias2[tid] = (tid < 128) ? b2[tid] : 0.0f;
    } else if (b < 513 + nqb) {
      int idx = (b - 513) * 256 + tid;
      if (idx < nquads) {
        int n = idx >> 5, q = idx & 31;
        float4 v = ((const float4*)x)[idx];
        ((uint2*)A1u)[(size_t)n * 64 + q] = make_uint2(pack2(v.x, v.y), pack2(v.z, v.w));
        int pk = __builtin_amdgcn_cvt_pk_fp8_f32(v.x, v.y, 0, false);
        pk = __builtin_amdgcn_cvt_pk_fp8_f32(v.z, v.w, pk, true);
        xf8[(size_t)n * 32 + q] = (unsigned)pk;
      }
    } else {
      for (int t = tid; t < NB; t += 256) counters[t] = 0;
    }
  }
  gsync(bar, G);

  // ---------- Phase B: bucket scatter ----------
  for (int b = blockIdx.x; b < SB; b += G) {
    int* h = sm;          // [512]
    int* base = sm + 512; // [512]
    for (int t = tid; t < NB; t += 256) h[t] = 0;
    __syncthreads();
    int start = b * EPB, end = min(E, start + EPB);
    for (int i = start + tid; i < end; i += 256) atomicAdd(&h[((unsigned)edst[i]) >> 7], 1);
    __syncthreads();
    for (int t = tid; t < NB; t += 256) {
      int c = h[t];
      base[t] = (c > 0) ? atomicAdd(&counters[t], c) : 0;
      h[t] = 0;
    }
    __syncthreads();
    for (int i = start + tid; i < end; i += 256) {
      unsigned d = (unsigned)edst[i];
      unsigned bk = d >> 7;
      int p = base[bk] + atomicAdd(&h[bk], 1);
      bedge[(size_t)bk * SLACK + p] = ((d & 127u) << 24) | (unsigned)esrc[i];
    }
    __syncthreads();
  }
  gsync(bar, 2 * G);

  // ---------- Phase C: build CSR ----------
  for (int b = blockIdx.x; b < NB; b += G) {
    int* buf = sm;  // [128]
    int cntE = counters[b];
    int rb = b * SLACK;
    if (tid < 128) buf[tid] = 0;
    __syncthreads();
    for (int i = tid; i < cntE; i += 256) atomicAdd(&buf[bedge[(size_t)rb + i] >> 24], 1);
    __syncthreads();
    int cnt = (tid < 128) ? buf[tid] : 0;
    #pragma unroll
    for (int off = 1; off < 128; off <<= 1) {
      int t = (tid >= off && tid < 128) ? buf[tid - off] : 0;
      __syncthreads();
      if (tid < 128) buf[tid] += t;
      __syncthreads();
    }
    if (tid < 128) {
      int excl_l = buf[tid] - cnt;
      int node = (b << 7) + tid;
      if (node < N) {
        offsets[node] = rb + excl_l;
        oend[node]    = rb + excl_l + cnt;
        inv_deg[node] = 1.0f / fmaxf((float)cnt, 1.0f);
      }
      buf[tid] = rb + excl_l;
    }
    __syncthreads();
    for (int i = tid; i < cntE; i += 256) {
      unsigned e2 = bedge[(size_t)rb + i];
      int p = atomicAdd(&buf[e2 >> 24], 1);
      ssrc[p] = (int)(e2 & 0xFFFFFFu);
    }
    __syncthreads();
  }
  gsync(bar, 3 * G);

  // ---------- Phase D: layer-1 aggregation ----------
  int ngrp = (N + 3) >> 2;
  int lane = tid & 63;
  int lg = lane >> 4;
  int l = lane & 15;
  for (int grp = blockIdx.x; grp < ngrp; grp += G) {
    int node = grp * 4 + (tid >> 6);
    if (node >= N) continue;
    int s = offsets[node], e = oend[node];
    float a0=0.f,a1=0.f,a2=0.f,a3=0.f,a4=0.f,a5=0.f,a6=0.f,a7=0.f;
    int i = s;
    for (; i + 16 <= e; i += 16) {
      int sA = ssrc[i + lg], sB = ssrc[i + 4 + lg];
      int sC = ssrc[i + 8 + lg], sD = ssrc[i + 12 + lg];
      uint2 u = ((const uint2*)xf8)[((size_t)(unsigned)sA << 4) + l];
      uint2 v = ((const uint2*)xf8)[((size_t)(unsigned)sB << 4) + l];
      uint2 w = ((const uint2*)xf8)[((size_t)(unsigned)sC << 4) + l];
      uint2 z = ((const uint2*)xf8)[((size_t)(unsigned)sD << 4) + l];
      f32x2 p_, q_;
      p_ = __builtin_amdgcn_cvt_pk_f32_fp8(u.x, false); q_ = __builtin_amdgcn_cvt_pk_f32_fp8(u.x, true);
      a0 += p_[0]; a1 += p_[1]; a2 += q_[0]; a3 += q_[1];
      p_ = __builtin_amdgcn_cvt_pk_f32_fp8(u.y, false); q_ = __builtin_amdgcn_cvt_pk_f32_fp8(u.y, true);
      a4 += p_[0]; a5 += p_[1]; a6 += q_[0]; a7 += q_[1];
      p_ = __builtin_amdgcn_cvt_pk_f32_fp8(v.x, false); q_ = __builtin_amdgcn_cvt_pk_f32_fp8(v.x, true);
      a0 += p_[0]; a1 += p_[1]; a2 += q_[0]; a3 += q_[1];
      p_ = __builtin_amdgcn_cvt_pk_f32_fp8(v.y, false); q_ = __builtin_amdgcn_cvt_pk_f32_fp8(v.y, true);
      a4 += p_[0]; a5 += p_[1]; a6 += q_[0]; a7 += q_[1];
      p_ = __builtin_amdgcn_cvt_pk_f32_fp8(w.x, false); q_ = __builtin_amdgcn_cvt_pk_f32_fp8(w.x, true);
      a0 += p_[0]; a1 += p_[1]; a2 += q_[0]; a3 += q_[1];
      p_ = __builtin_amdgcn_cvt_pk_f32_fp8(w.y, false); q_ = __builtin_amdgcn_cvt_pk_f32_fp8(w.y, true);
      a4 += p_[0]; a5 += p_[1]; a6 += q_[0]; a7 += q_[1];
      p_ = __builtin_amdgcn_cvt_pk_f32_fp8(z.x, false); q_ = __builtin_amdgcn_cvt_pk_f32_fp8(z.x, true);
      a0 += p_[0]; a1 += p_[1]; a2 += q_[0]; a3 += q_[1];
      p_ = __builtin_amdgcn_cvt_pk_f32_fp8(z.y, false); q_ = __builtin_amdgcn_cvt_pk_f32_fp8(z.y, true);
      a4 += p_[0]; a5 += p_[1]; a6 += q_[0]; a7 += q_[1];
    }
    for (; i < e; i += 4) {
      if (lg < e - i) {
        uint2 u = ((const uint2*)xf8)[((size_t)(unsigned)ssrc[i + lg] << 4) + l];
        f32x2 p_, q_;
        p_ = __builtin_amdgcn_cvt_pk_f32_fp8(u.x, false); q_ = __builtin_amdgcn_cvt_pk_f32_fp8(u.x, true);
        a0 += p_[0]; a1 += p_[1]; a2 += q_[0]; a3 += q_[1];
        p_ = __builtin_amdgcn_cvt_pk_f32_fp8(u.y, false); q_ = __builtin_amdgcn_cvt_pk_f32_fp8(u.y, true);
        a4 += p_[0]; a5 += p_[1]; a6 += q_[0]; a7 += q_[1];
      }
    }
    a0 += __shfl_xor(a0,16,64); a0 += __shfl_xor(a0,32,64);
    a1 += __shfl_xor(a1,16,64); a1 += __shfl_xor(a1,32,64);
    a2 += __shfl_xor(a2,16,64); a2 += __shfl_xor(a2,32,64);
    a3 += __shfl_xor(a3,16,64); a3 += __shfl_xor(a3,32,64);
    a4 += __shfl_xor(a4,16,64); a4 += __shfl_xor(a4,32,64);
    a5 += __shfl_xor(a5,16,64); a5 += __shfl_xor(a5,32,64);
    a6 += __shfl_xor(a6,16,64); a6 += __shfl_xor(a6,32,64);
    a7 += __shfl_xor(a7,16,64); a7 += __shfl_xor(a7,32,64);
    if (lg == 0) {
      float id = inv_deg[node];
      ((uint4*)A1u)[((size_t)node << 5) + 16 + l] =
          make_uint4(pack2(a0 * id, a1 * id), pack2(a2 * id, a3 * id),
                     pack2(a4 * id, a5 * id), pack2(a6 * id, a7 * id));
    }
  }
}

// ================= register-resident bf16 MFMA GEMM (no LDS, no barriers) ===========
__global__ __launch_bounds__(256, 2) void gemm_mfma(const short* __restrict__ A,
                                                    const short* __restrict__ Bp,
                                                    const float* __restrict__ bias,
                                                    void* __restrict__ out0,
                                                    void* __restrict__ out1,
                                                    int S, int mode) {
  int tid = threadIdx.x;
  int w = tid >> 6;
  int lane = tid & 63;

  bf16x8 breg[8][4];
  #pragma unroll
  for (int kb = 0; kb < 8; ++kb)
    #pragma unroll
    for (int j = 0; j < 4; ++j)
      breg[kb][j] = *(const bf16x8*)(Bp + ((size_t)((kb * 16 + w * 4 + j) * 64 + lane)) * 8);

  float bj[4];
  #pragma unroll
  for (int j = 0; j < 4; ++j) bj[j] = bias[w * 64 + j * 16 + (lane & 15)];

  int rowInFrag = lane & 15;
  int kseg = (lane >> 4) * 8;

  for (int s = blockIdx.x; s < S; s += gridDim.x) {
    int row0 = s * 16;
    const short* Arow = A + (size_t)(row0 + rowInFrag) * 256 + kseg;
    bf16x8 afr[8];
    #pragma unroll
    for (int kb = 0; kb < 8; ++kb) afr[kb] = *(const bf16x8*)(Arow + kb * 32);

    f32x4 acc[4];
    #pragma unroll
    for (int j = 0; j < 4; ++j) acc[j] = (f32x4)(0.0f);
    #pragma unroll
    for (int kb = 0; kb < 8; ++kb)
      #pragma unroll
      for (int j = 0; j < 4; ++j)
        acc[j] = __builtin_amdgcn_mfma_f32_16x16x32_bf16(afr[kb], breg[kb][j], acc[j], 0, 0, 0);

    int crow0 = row0 + (lane >> 4) * 4;
    int ccol = lane & 15;
    #pragma unroll
    for (int j = 0; j < 4; ++j) {
      int col = w * 64 + j * 16 + ccol;
      #pragma unroll
      for (int r = 0; r < 4; ++r) {
        float v = acc[j][r] + bj[j];
        int row = crow0 + r;
        if (mode == 0) {
          ((short*)out0)[(size_t)row * 256 + col] = bf16_rne(fmaxf(v, 0.0f));
        } else if (w < 2) {
          ((short*)out0)[(size_t)row * 128 + col] = bf16_rne(v);
        } else {
          int pk = __builtin_amdgcn_cvt_pk_fp8_f32(v, v, 0, false);
          ((unsigned char*)out1)[(size_t)row * 128 + (col - 128)] = (unsigned char)(pk & 0xff);
        }
      }
    }
  }
}

// ================= fused final: quad-mode fp8 gather + bf16 utop + log_softmax =======
#define CVT8(U, A0, A1, A2, A3, A4, A5, A6, A7)                                        \
  {                                                                                    \
    f32x2 p_, q_;                                                                      \
    p_ = __builtin_amdgcn_cvt_pk_f32_fp8((U).x, false);                                \
    q_ = __builtin_amdgcn_cvt_pk_f32_fp8((U).x, true);                                 \
    A0 += p_[0]; A1 += p_[1]; A2 += q_[0]; A3 += q_[1];                                \
    p_ = __builtin_amdgcn_cvt_pk_f32_fp8((U).y, false);                                \
    q_ = __builtin_amdgcn_cvt_pk_f32_fp8((U).y, true);                                 \
    A4 += p_[0]; A5 += p_[1]; A6 += q_[0]; A7 += q_[1];                                \
  }

__global__ __launch_bounds__(256) void final_kernel(const uint4* __restrict__ utopq,
                                                    const uint2* __restrict__ T2,
                                                    const int* __restrict__ offsets,
                                                    const int* __restrict__ oend,
                                                    const int* __restrict__ ssrc,
                                                    const float* __restrict__ inv_deg,
                                                    float4* __restrict__ out4, int N) {
  int node = blockIdx.x * 4 + (threadIdx.x >> 6);
  if (node >= N) return;
  int lane = threadIdx.x & 63;
  int g = lane >> 4;
  int l = lane & 15;
  int s = offsets[node], e = oend[node];
  float a0=0.f,a1=0.f,a2=0.f,a3=0.f,a4=0.f,a5=0.f,a6=0.f,a7=0.f;
  int i = s;
  for (; i + 16 <= e; i += 16) {
    int sA = ssrc[i + g], sB = ssrc[i + 4 + g];
    int sC = ssrc[i + 8 + g], sD = ssrc[i + 12 + g];
    uint2 u = T2[((size_t)(unsigned)sA << 4) + l];
    uint2 v = T2[((size_t)(unsigned)sB << 4) + l];
    uint2 w = T2[((size_t)(unsigned)sC << 4) + l];
    uint2 z = T2[((size_t)(unsigned)sD << 4) + l];
    CVT8(u, a0,a1,a2,a3,a4,a5,a6,a7);
    CVT8(v, a0,a1,a2,a3,a4,a5,a6,a7);
    CVT8(w, a0,a1,a2,a3,a4,a5,a6,a7);
    CVT8(z, a0,a1,a2,a3,a4,a5,a6,a7);
  }
  for (; i < e; i += 4) {
    if (g < e - i) {
      uint2 u = T2[((size_t)(unsigned)ssrc[i + g] << 4) + l];
      CVT8(u, a0,a1,a2,a3,a4,a5,a6,a7);
    }
  }
  a0 += __shfl_xor(a0,16,64); a0 += __shfl_xor(a0,32,64);
  a1 += __shfl_xor(a1,16,64); a1 += __shfl_xor(a1,32,64);
  a2 += __shfl_xor(a2,16,64); a2 += __shfl_xor(a2,32,64);
  a3 += __shfl_xor(a3,16,64); a3 += __shfl_xor(a3,32,64);
  a4 += __shfl_xor(a4,16,64); a4 += __shfl_xor(a4,32,64);
  a5 += __shfl_xor(a5,16,64); a5 += __shfl_xor(a5,32,64);
  a6 += __shfl_xor(a6,16,64); a6 += __shfl_xor(a6,32,64);
  a7 += __shfl_xor(a7,16,64); a7 += __shfl_xor(a7,32,64);
  if (g == 0) {
    float id = inv_deg[node];
    uint4 U = utopq[((size_t)node << 4) + l];
    float v0 = bf16lo(U.x) + a0 * id;
    float v1 = bf16hi(U.x) + a1 * id;
    float v2 = bf16lo(U.y) + a2 * id;
    float v3 = bf16hi(U.y) + a3 * id;
    float v4 = bf16lo(U.z) + a4 * id;
    float v5 = bf16hi(U.z) + a5 * id;
    float v6 = bf16lo(U.w) + a6 * id;
    float v7 = bf16hi(U.w) + a7 * id;
    float m = fmaxf(fmaxf(fmaxf(v0, v1), fmaxf(v2, v3)), fmaxf(fmaxf(v4, v5), fmaxf(v6, v7)));
    #pragma unroll
    for (int off = 1; off < 16; off <<= 1) m = fmaxf(m, __shfl_xor(m, off, 16));
    float su = expf(v0 - m) + expf(v1 - m) + expf(v2 - m) + expf(v3 - m) +
               expf(v4 - m) + expf(v5 - m) + expf(v6 - m) + expf(v7 - m);
    #pragma unroll
    for (int off = 1; off < 16; off <<= 1) su += __shfl_xor(su, off, 16);
    float ls = m + logf(su);
    out4[((size_t)node << 5) + l * 2]     = make_float4(v0 - ls, v1 - ls, v2 - ls, v3 - ls);
    out4[((size_t)node << 5) + l * 2 + 1] = make_float4(v4 - ls, v5 - ls, v6 - ls, v7 - ls);
  }
}

extern "C" void kernel_launch(void* const* d_in, const int* in_sizes, int n_in,
                              void* d_out, int out_size, void* d_ws, size_t ws_size,
                              hipStream_t stream) {
  const float* x        = (const float*)d_in[0];
  const int*   edge_src = (const int*)d_in[1];
  const int*   edge_dst = (const int*)d_in[2];
  const float* W1       = (const float*)d_in[3];
  const float* b1       = (const float*)d_in[4];
  const float* W2       = (const float*)d_in[5];
  const float* b2       = (const float*)d_in[6];
  float* out = (float*)d_out;

  const int D_IN = 128;
  const int N = in_sizes[0] / D_IN;
  const int E = in_sizes[1];
  const int M_pad = ((N + 127) / 128) * 128;

  const int SB = 512;                    // edge-chunk units
  const int EPB = (E + SB - 1) / SB;
  const int NB = (N + 127) >> 7;         // node buckets (128 nodes each)
  const int SLACK = 3072;                // slots per bucket region (mean ~2048, +22 sigma)
  const int GRID = 1536;                 // 6 blocks/CU x 256 CUs, co-resident by launch_bounds

  char* ws = (char*)d_ws;
  size_t p = 0;
  auto take = [&](size_t bytes) -> size_t {
    size_t r = p;
    p += (bytes + 255) & ~(size_t)255;
    return r;
  };
  size_t bar_off   = take(256);
  size_t cnt_off   = take((size_t)NB * 4);
  size_t bedge_off = take((size_t)NB * SLACK * 4);
  size_t offs_off  = take((size_t)N * 4);
  size_t oend_off  = take((size_t)N * 4);
  size_t inv_off   = take((size_t)N * 4);
  size_t ssrc_off  = take((size_t)NB * SLACK * 4);
  size_t A1_off    = take((size_t)M_pad * 256 * 2);   // bf16 [x | agg1]
  size_t xf8_off   = take((size_t)M_pad * 128);       // fp8 x gather table
  size_t h_off     = take((size_t)M_pad * 256 * 2);   // bf16 h
  size_t B1p_off   = take((size_t)256 * 256 * 2);
  size_t B2p_off   = take((size_t)256 * 256 * 2);
  size_t bias2_off = take((size_t)256 * 4);
  size_t utop_off  = take((size_t)M_pad * 128 * 2);   // bf16
  size_t t2_off    = take((size_t)M_pad * 128);       // fp8
  (void)ws_size;

  int*   bar      = (int*)(ws + bar_off);
  int*   counters = (int*)(ws + cnt_off);
  unsigned* bedge = (unsigned*)(ws + bedge_off);
  int*   offsets  = (int*)(ws + offs_off);
  int*   oendp    = (int*)(ws + oend_off);
  float* inv_deg  = (float*)(ws + inv_off);
  int*   ssrc     = (int*)(ws + ssrc_off);
  unsigned* A1u   = (unsigned*)(ws + A1_off);
  unsigned* xf8   = (unsigned*)(ws + xf8_off);
  short* h        = (short*)(ws + h_off);
  short* B1p      = (short*)(ws + B1p_off);
  short* B2p      = (short*)(ws + B2p_off);
  float* bias2    = (float*)(ws + bias2_off);
  short* utop     = (short*)(ws + utop_off);
  unsigned char* t2f8 = (unsigned char*)(ws + t2_off);

  // zero the grid-barrier counter (captured in graph)
  hipMemsetAsync(bar, 0, 4, stream);

  // ---- fused pipeline: prep -> scatter -> build_csr -> agg1 (3 device barriers) ----
  {
    int nquads = N * 32;
    pipeline_kernel<<<GRID, 256, 0, stream>>>(W1, W2, b2, x, B1p, B2p, bias2, A1u, xf8, nquads,
                                              edge_src, edge_dst, E, EPB, counters, NB, SLACK,
                                              bedge, SB, offsets, oendp, inv_deg, ssrc, N, bar);
  }
  // ---- GEMMs ----
  {
    int S = M_pad / 16;
    gemm_mfma<<<1024, 256, 0, stream>>>((const short*)A1u, B1p, b1, h, nullptr, S, 0);
    gemm_mfma<<<1024, 256, 0, stream>>>(h, B2p, bias2, utop, t2f8, S, 1);
  }
  // ---- fused aggregate + log_softmax ----
  final_kernel<<<(N + 3) / 4, 256, 0, stream>>>((const uint4*)utop, (const uint2*)t2f8,
                                                offsets, oendp, ssrc, inv_deg, (float4*)out, N);
}

// Round 13
// 220.145 us; speedup vs baseline: 3.1115x; 3.1115x over previous
//
#include <hip/hip_runtime.h>
#include <cstdint>
#include <cstddef>

typedef __attribute__((ext_vector_type(8))) short bf16x8;
typedef __attribute__((ext_vector_type(4))) float f32x4;
typedef __attribute__((ext_vector_type(2))) float f32x2;

__device__ inline short bf16_rne(float f) {
  unsigned u = __builtin_bit_cast(unsigned, f);
  u += 0x7fff + ((u >> 16) & 1);
  return (short)(u >> 16);
}

__device__ inline float bf16lo(unsigned v) { return __builtin_bit_cast(float, v << 16); }
__device__ inline float bf16hi(unsigned v) { return __builtin_bit_cast(float, v & 0xffff0000u); }

__device__ inline unsigned pack2(float a, float b) {
  return ((unsigned)(unsigned short)bf16_rne(a)) | (((unsigned)(unsigned short)bf16_rne(b)) << 16);
}

// ================= CSR build: slack-region reservation sort =================
// Buckets of 128 nodes (bucket = dst >> 7), each with a SLACK-slot region.

// fused prep: pack W1/W2 + bias2 + convert x (bf16 + fp8) + zero bucket counters
__global__ __launch_bounds__(256) void prep_kernel(const float* __restrict__ W1,
                                                   const float* __restrict__ W2,
                                                   const float* __restrict__ b2,
                                                   const float* __restrict__ x,
                                                   short* __restrict__ B1p,
                                                   short* __restrict__ B2p,
                                                   float* __restrict__ bias2,
                                                   unsigned* __restrict__ A1u,
                                                   unsigned* __restrict__ xf8, int nquads,
                                                   int* __restrict__ counters, int NB) {
  int b = blockIdx.x;
  int tid = threadIdx.x;
  int nqb = (nquads + 255) >> 8;
  if (b < 512) {
    int mode = b >> 8;
    int idx = (b & 255) * 256 + tid;  // 65536 per weight
    int j = idx & 7;
    int L = (idx >> 3) & 63;
    int nt = (idx >> 9) & 15;
    int kb = idx >> 13;
    int k = kb * 32 + (L >> 4) * 8 + j;
    int n = nt * 16 + (L & 15);
    if (mode == 0) {
      B1p[idx] = bf16_rne(W1[(size_t)k * 256 + n]);
    } else {
      float v = (n < 128) ? W2[(size_t)k * 128 + n] : W2[(size_t)(256 + k) * 128 + (n - 128)];
      B2p[idx] = bf16_rne(v);
    }
  } else if (b == 512) {
    bias2[tid] = (tid < 128) ? b2[tid] : 0.0f;
  } else if (b < 513 + nqb) {
    int idx = (b - 513) * 256 + tid;  // quad of 4 floats
    if (idx < nquads) {
      int n = idx >> 5, q = idx & 31;
      float4 v = ((const float4*)x)[idx];
      ((uint2*)A1u)[(size_t)n * 64 + q] = make_uint2(pack2(v.x, v.y), pack2(v.z, v.w));
      int pk = __builtin_amdgcn_cvt_pk_fp8_f32(v.x, v.y, 0, false);
      pk = __builtin_amdgcn_cvt_pk_fp8_f32(v.z, v.w, pk, true);
      xf8[(size_t)n * 32 + q] = (unsigned)pk;
    }
  } else {
    for (int t = tid; t < NB; t += 256) counters[t] = 0;
  }
}

// scatter packed (dst&127,src) into per-bucket slack regions
__global__ __launch_bounds__(256) void bucket_scatter(const int* __restrict__ src,
                                                      const int* __restrict__ dst, int E, int EPB,
                                                      int* __restrict__ counters, int NB,
                                                      int SLACK, unsigned* __restrict__ bedge) {
  __shared__ int h[512];
  __shared__ int base[512];
  int tid = threadIdx.x;
  for (int t = tid; t < NB; t += 256) h[t] = 0;
  __syncthreads();
  int start = blockIdx.x * EPB, end = min(E, start + EPB);
  for (int i = start + tid; i < end; i += 256) atomicAdd(&h[((unsigned)dst[i]) >> 7], 1);
  __syncthreads();
  for (int t = tid; t < NB; t += 256) {
    int c = h[t];
    base[t] = (c > 0) ? atomicAdd(&counters[t], c) : 0;
    h[t] = 0;  // reuse as local cursor
  }
  __syncthreads();
  for (int i = start + tid; i < end; i += 256) {
    unsigned d = (unsigned)dst[i];
    unsigned bk = d >> 7;
    int p = base[bk] + atomicAdd(&h[bk], 1);
    bedge[(size_t)bk * SLACK + p] = ((d & 127u) << 24) | (unsigned)src[i];
  }
}

// per-bucket CSR finalize (128 nodes per bucket), slack layout
__global__ __launch_bounds__(256) void build_csr(const unsigned* __restrict__ bedge,
                                                 const int* __restrict__ counters,
                                                 int NB, int SLACK, int N,
                                                 int* __restrict__ offsets,
                                                 int* __restrict__ oend,
                                                 float* __restrict__ inv_deg,
                                                 int* __restrict__ ssrc) {
  __shared__ int buf[128];
  int b = blockIdx.x, tid = threadIdx.x;
  int cntE = counters[b];
  int rb = b * SLACK;
  if (tid < 128) buf[tid] = 0;
  __syncthreads();
  for (int i = tid; i < cntE; i += 256) atomicAdd(&buf[bedge[(size_t)rb + i] >> 24], 1);
  __syncthreads();
  int cnt = (tid < 128) ? buf[tid] : 0;
  #pragma unroll
  for (int off = 1; off < 128; off <<= 1) {
    int t = (tid >= off && tid < 128) ? buf[tid - off] : 0;
    __syncthreads();
    if (tid < 128) buf[tid] += t;
    __syncthreads();
  }
  if (tid < 128) {
    int excl_l = buf[tid] - cnt;
    int node = (b << 7) + tid;
    if (node < N) {
      offsets[node] = rb + excl_l;
      oend[node]    = rb + excl_l + cnt;
      inv_deg[node] = 1.0f / fmaxf((float)cnt, 1.0f);
    }
    buf[tid] = rb + excl_l;  // cursor
  }
  __syncthreads();
  for (int i = tid; i < cntE; i += 256) {
    unsigned e2 = bedge[(size_t)rb + i];
    int p = atomicAdd(&buf[e2 >> 24], 1);
    ssrc[p] = (int)(e2 & 0xFFFFFFu);
  }
}

// ================= quad-mode fp8 gathers =================
#define CVT8(U, A0, A1, A2, A3, A4, A5, A6, A7)                                        \
  {                                                                                    \
    f32x2 p_, q_;                                                                      \
    p_ = __builtin_amdgcn_cvt_pk_f32_fp8((U).x, false);                                \
    q_ = __builtin_amdgcn_cvt_pk_f32_fp8((U).x, true);                                 \
    A0 += p_[0]; A1 += p_[1]; A2 += q_[0]; A3 += q_[1];                                \
    p_ = __builtin_amdgcn_cvt_pk_f32_fp8((U).y, false);                                \
    q_ = __builtin_amdgcn_cvt_pk_f32_fp8((U).y, true);                                 \
    A4 += p_[0]; A5 += p_[1]; A6 += q_[0]; A7 += q_[1];                                \
  }

// layer-1 aggregation: wave per node, writes bf16 into A1 right half
__global__ __launch_bounds__(256) void agg1_kernel(const uint2* __restrict__ X8,
                                                   const int* __restrict__ offsets,
                                                   const int* __restrict__ oend,
                                                   const int* __restrict__ ssrc,
                                                   const float* __restrict__ inv_deg,
                                                   uint4* __restrict__ A1q, int N) {
  int node = blockIdx.x * 4 + (threadIdx.x >> 6);
  if (node >= N) return;
  int lane = threadIdx.x & 63;
  int g = lane >> 4;
  int l = lane & 15;
  int s = offsets[node], e = oend[node];
  float a0=0.f,a1=0.f,a2=0.f,a3=0.f,a4=0.f,a5=0.f,a6=0.f,a7=0.f;
  int i = s;
  for (; i + 16 <= e; i += 16) {
    int sA = ssrc[i + g], sB = ssrc[i + 4 + g];
    int sC = ssrc[i + 8 + g], sD = ssrc[i + 12 + g];
    uint2 u = X8[((size_t)(unsigned)sA << 4) + l];
    uint2 v = X8[((size_t)(unsigned)sB << 4) + l];
    uint2 w = X8[((size_t)(unsigned)sC << 4) + l];
    uint2 z = X8[((size_t)(unsigned)sD << 4) + l];
    CVT8(u, a0,a1,a2,a3,a4,a5,a6,a7);
    CVT8(v, a0,a1,a2,a3,a4,a5,a6,a7);
    CVT8(w, a0,a1,a2,a3,a4,a5,a6,a7);
    CVT8(z, a0,a1,a2,a3,a4,a5,a6,a7);
  }
  for (; i < e; i += 4) {
    if (g < e - i) {
      uint2 u = X8[((size_t)(unsigned)ssrc[i + g] << 4) + l];
      CVT8(u, a0,a1,a2,a3,a4,a5,a6,a7);
    }
  }
  a0 += __shfl_xor(a0,16,64); a0 += __shfl_xor(a0,32,64);
  a1 += __shfl_xor(a1,16,64); a1 += __shfl_xor(a1,32,64);
  a2 += __shfl_xor(a2,16,64); a2 += __shfl_xor(a2,32,64);
  a3 += __shfl_xor(a3,16,64); a3 += __shfl_xor(a3,32,64);
  a4 += __shfl_xor(a4,16,64); a4 += __shfl_xor(a4,32,64);
  a5 += __shfl_xor(a5,16,64); a5 += __shfl_xor(a5,32,64);
  a6 += __shfl_xor(a6,16,64); a6 += __shfl_xor(a6,32,64);
  a7 += __shfl_xor(a7,16,64); a7 += __shfl_xor(a7,32,64);
  if (g == 0) {
    float id = inv_deg[node];
    A1q[((size_t)node << 5) + 16 + l] =
        make_uint4(pack2(a0 * id, a1 * id), pack2(a2 * id, a3 * id),
                   pack2(a4 * id, a5 * id), pack2(a6 * id, a7 * id));
  }
}

// ================= register-resident bf16 MFMA GEMM (no LDS, no barriers) ===========
// B (K=256 x N=256 bf16 = 128 KB) lives in registers: wave w holds its 64 output
// cols' full B panel in breg[8][4] (128 VGPRs). A-frags stream global->VGPR in the
// exact MFMA A-operand layout. Grid-strides over 16-row strips.
// mode 0: out0 = bf16 relu(acc+bias) [M,256]
// mode 1: waves 0-1 -> out0 bf16 [M,128] (utop); waves 2-3 -> out1 fp8 [M,128] (t2)
__global__ __launch_bounds__(256, 2) void gemm_mfma(const short* __restrict__ A,
                                                    const short* __restrict__ Bp,
                                                    const float* __restrict__ bias,
                                                    void* __restrict__ out0,
                                                    void* __restrict__ out1,
                                                    int S, int mode) {
  int tid = threadIdx.x;
  int w = tid >> 6;      // wave 0..3 -> cols 64w..64w+63
  int lane = tid & 63;

  bf16x8 breg[8][4];
  #pragma unroll
  for (int kb = 0; kb < 8; ++kb)
    #pragma unroll
    for (int j = 0; j < 4; ++j)
      breg[kb][j] = *(const bf16x8*)(Bp + ((size_t)((kb * 16 + w * 4 + j) * 64 + lane)) * 8);

  float bj[4];
  #pragma unroll
  for (int j = 0; j < 4; ++j) bj[j] = bias[w * 64 + j * 16 + (lane & 15)];

  int rowInFrag = lane & 15;
  int kseg = (lane >> 4) * 8;

  for (int s = blockIdx.x; s < S; s += gridDim.x) {
    int row0 = s * 16;
    const short* Arow = A + (size_t)(row0 + rowInFrag) * 256 + kseg;
    bf16x8 afr[8];
    #pragma unroll
    for (int kb = 0; kb < 8; ++kb) afr[kb] = *(const bf16x8*)(Arow + kb * 32);

    f32x4 acc[4];
    #pragma unroll
    for (int j = 0; j < 4; ++j) acc[j] = (f32x4)(0.0f);
    #pragma unroll
    for (int kb = 0; kb < 8; ++kb)
      #pragma unroll
      for (int j = 0; j < 4; ++j)
        acc[j] = __builtin_amdgcn_mfma_f32_16x16x32_bf16(afr[kb], breg[kb][j], acc[j], 0, 0, 0);

    int crow0 = row0 + (lane >> 4) * 4;
    int ccol = lane & 15;
    #pragma unroll
    for (int j = 0; j < 4; ++j) {
      int col = w * 64 + j * 16 + ccol;
      #pragma unroll
      for (int r = 0; r < 4; ++r) {
        float v = acc[j][r] + bj[j];
        int row = crow0 + r;
        if (mode == 0) {
          ((short*)out0)[(size_t)row * 256 + col] = bf16_rne(fmaxf(v, 0.0f));
        } else if (w < 2) {
          ((short*)out0)[(size_t)row * 128 + col] = bf16_rne(v);
        } else {
          int pk = __builtin_amdgcn_cvt_pk_fp8_f32(v, v, 0, false);
          ((unsigned char*)out1)[(size_t)row * 128 + (col - 128)] = (unsigned char)(pk & 0xff);
        }
      }
    }
  }
}

// ================= fused final: quad-mode fp8 gather + bf16 utop + log_softmax =======
__global__ __launch_bounds__(256) void final_kernel(const uint4* __restrict__ utopq,
                                                    const uint2* __restrict__ T2,
                                                    const int* __restrict__ offsets,
                                                    const int* __restrict__ oend,
                                                    const int* __restrict__ ssrc,
                                                    const float* __restrict__ inv_deg,
                                                    float4* __restrict__ out4, int N) {
  int node = blockIdx.x * 4 + (threadIdx.x >> 6);
  if (node >= N) return;
  int lane = threadIdx.x & 63;
  int g = lane >> 4;
  int l = lane & 15;
  int s = offsets[node], e = oend[node];
  float a0=0.f,a1=0.f,a2=0.f,a3=0.f,a4=0.f,a5=0.f,a6=0.f,a7=0.f;
  int i = s;
  for (; i + 16 <= e; i += 16) {
    int sA = ssrc[i + g], sB = ssrc[i + 4 + g];
    int sC = ssrc[i + 8 + g], sD = ssrc[i + 12 + g];
    uint2 u = T2[((size_t)(unsigned)sA << 4) + l];
    uint2 v = T2[((size_t)(unsigned)sB << 4) + l];
    uint2 w = T2[((size_t)(unsigned)sC << 4) + l];
    uint2 z = T2[((size_t)(unsigned)sD << 4) + l];
    CVT8(u, a0,a1,a2,a3,a4,a5,a6,a7);
    CVT8(v, a0,a1,a2,a3,a4,a5,a6,a7);
    CVT8(w, a0,a1,a2,a3,a4,a5,a6,a7);
    CVT8(z, a0,a1,a2,a3,a4,a5,a6,a7);
  }
  for (; i < e; i += 4) {
    if (g < e - i) {
      uint2 u = T2[((size_t)(unsigned)ssrc[i + g] << 4) + l];
      CVT8(u, a0,a1,a2,a3,a4,a5,a6,a7);
    }
  }
  a0 += __shfl_xor(a0,16,64); a0 += __shfl_xor(a0,32,64);
  a1 += __shfl_xor(a1,16,64); a1 += __shfl_xor(a1,32,64);
  a2 += __shfl_xor(a2,16,64); a2 += __shfl_xor(a2,32,64);
  a3 += __shfl_xor(a3,16,64); a3 += __shfl_xor(a3,32,64);
  a4 += __shfl_xor(a4,16,64); a4 += __shfl_xor(a4,32,64);
  a5 += __shfl_xor(a5,16,64); a5 += __shfl_xor(a5,32,64);
  a6 += __shfl_xor(a6,16,64); a6 += __shfl_xor(a6,32,64);
  a7 += __shfl_xor(a7,16,64); a7 += __shfl_xor(a7,32,64);
  if (g == 0) {
    float id = inv_deg[node];
    uint4 U = utopq[((size_t)node << 4) + l];
    float v0 = bf16lo(U.x) + a0 * id;
    float v1 = bf16hi(U.x) + a1 * id;
    float v2 = bf16lo(U.y) + a2 * id;
    float v3 = bf16hi(U.y) + a3 * id;
    float v4 = bf16lo(U.z) + a4 * id;
    float v5 = bf16hi(U.z) + a5 * id;
    float v6 = bf16lo(U.w) + a6 * id;
    float v7 = bf16hi(U.w) + a7 * id;
    float m = fmaxf(fmaxf(fmaxf(v0, v1), fmaxf(v2, v3)), fmaxf(fmaxf(v4, v5), fmaxf(v6, v7)));
    #pragma unroll
    for (int off = 1; off < 16; off <<= 1) m = fmaxf(m, __shfl_xor(m, off, 16));
    float su = expf(v0 - m) + expf(v1 - m) + expf(v2 - m) + expf(v3 - m) +
               expf(v4 - m) + expf(v5 - m) + expf(v6 - m) + expf(v7 - m);
    #pragma unroll
    for (int off = 1; off < 16; off <<= 1) su += __shfl_xor(su, off, 16);
    float ls = m + logf(su);
    out4[((size_t)node << 5) + l * 2]     = make_float4(v0 - ls, v1 - ls, v2 - ls, v3 - ls);
    out4[((size_t)node << 5) + l * 2 + 1] = make_float4(v4 - ls, v5 - ls, v6 - ls, v7 - ls);
  }
}

extern "C" void kernel_launch(void* const* d_in, const int* in_sizes, int n_in,
                              void* d_out, int out_size, void* d_ws, size_t ws_size,
                              hipStream_t stream) {
  const float* x        = (const float*)d_in[0];
  const int*   edge_src = (const int*)d_in[1];
  const int*   edge_dst = (const int*)d_in[2];
  const float* W1       = (const float*)d_in[3];
  const float* b1       = (const float*)d_in[4];
  const float* W2       = (const float*)d_in[5];
  const float* b2       = (const float*)d_in[6];
  float* out = (float*)d_out;

  const int D_IN = 128;
  const int N = in_sizes[0] / D_IN;
  const int E = in_sizes[1];
  const int M_pad = ((N + 127) / 128) * 128;

  const int SB = 512;                    // edge-chunk blocks
  const int EPB = (E + SB - 1) / SB;     // edges per chunk
  const int NB = (N + 127) >> 7;         // node buckets (128 nodes each)
  const int SLACK = 3072;                // slots per bucket region (mean ~2048, +22 sigma)

  char* ws = (char*)d_ws;
  size_t p = 0;
  auto take = [&](size_t bytes) -> size_t {
    size_t r = p;
    p += (bytes + 255) & ~(size_t)255;
    return r;
  };
  size_t cnt_off   = take((size_t)NB * 4);
  size_t bedge_off = take((size_t)NB * SLACK * 4);    // slack regions, packed 4B/edge
  size_t offs_off  = take((size_t)N * 4);
  size_t oend_off  = take((size_t)N * 4);
  size_t inv_off   = take((size_t)N * 4);
  size_t ssrc_off  = take((size_t)NB * SLACK * 4);    // slack layout
  size_t A1_off    = take((size_t)M_pad * 256 * 2);   // bf16 [x | agg1]
  size_t xf8_off   = take((size_t)M_pad * 128);       // fp8 x gather table
  size_t h_off     = take((size_t)M_pad * 256 * 2);   // bf16 h
  size_t B1p_off   = take((size_t)256 * 256 * 2);
  size_t B2p_off   = take((size_t)256 * 256 * 2);
  size_t bias2_off = take((size_t)256 * 4);
  size_t utop_off  = take((size_t)M_pad * 128 * 2);   // bf16
  size_t t2_off    = take((size_t)M_pad * 128);       // fp8
  (void)ws_size;

  int*   counters = (int*)(ws + cnt_off);
  unsigned* bedge = (unsigned*)(ws + bedge_off);
  int*   offsets  = (int*)(ws + offs_off);
  int*   oendp    = (int*)(ws + oend_off);
  float* inv_deg  = (float*)(ws + inv_off);
  int*   ssrc     = (int*)(ws + ssrc_off);
  unsigned* A1u   = (unsigned*)(ws + A1_off);
  unsigned* xf8   = (unsigned*)(ws + xf8_off);
  short* h        = (short*)(ws + h_off);
  short* B1p      = (short*)(ws + B1p_off);
  short* B2p      = (short*)(ws + B2p_off);
  float* bias2    = (float*)(ws + bias2_off);
  short* utop     = (short*)(ws + utop_off);
  unsigned char* t2f8 = (unsigned char*)(ws + t2_off);

  // ---- fused prep (weight pack + bias2 + x convert + counter zero) ----
  {
    int nquads = N * 32;
    int grid = 513 + (nquads + 255) / 256 + 1;
    prep_kernel<<<grid, 256, 0, stream>>>(W1, W2, b2, x, B1p, B2p, bias2, A1u, xf8, nquads,
                                          counters, NB);
  }
  // ---- CSR build (no scan) ----
  bucket_scatter<<<SB, 256, 0, stream>>>(edge_src, edge_dst, E, EPB, counters, NB, SLACK, bedge);
  build_csr<<<NB, 256, 0, stream>>>(bedge, counters, NB, SLACK, N, offsets, oendp, inv_deg, ssrc);

  // ---- layer 1 ----
  agg1_kernel<<<(N + 3) / 4, 256, 0, stream>>>((const uint2*)xf8, offsets, oendp, ssrc, inv_deg,
                                               (uint4*)A1u, N);
  {
    int S = M_pad / 16;
    gemm_mfma<<<1024, 256, 0, stream>>>((const short*)A1u, B1p, b1, h, nullptr, S, 0);
    gemm_mfma<<<1024, 256, 0, stream>>>(h, B2p, bias2, utop, t2f8, S, 1);
  }
  // ---- fused aggregate + log_softmax ----
  final_kernel<<<(N + 3) / 4, 256, 0, stream>>>((const uint4*)utop, (const uint2*)t2f8,
                                                offsets, oendp, ssrc, inv_deg, (float4*)out, N);
}